// Round 9
// baseline (20.700 us; speedup 1.0000x reference)
//
#include <hip/hip_runtime.h>
#include <math.h>

#define EPSF 1e-8f

constexpr int B = 512;
constexpr int F = 256;

using frag_ab = __attribute__((ext_vector_type(8))) short;   // 8 bf16
using f32x4   = __attribute__((ext_vector_type(4))) float;

__device__ __forceinline__ unsigned short f2bf(float f) {
    unsigned int u = __float_as_uint(f);
    unsigned int r = (u + 0x7fffu + ((u >> 16) & 1u)) >> 16;   // RNE
    return (unsigned short)r;
}

// ---- K1: bf16 Gram tile GEMM, 1 wave per 16x16 tile, 1024 blocks ----------
// R7's proven tile kernel with the fp32->bf16 convert fused into staging
// (NO norms, NO cross-lane ops — that was R8's mistake). Also zeroes out[0].
__global__ __launch_bounds__(64) void gram_mfma(
    const float* __restrict__ feats, float* __restrict__ gram,
    float* __restrict__ out)
{
    const int bid = blockIdx.x;
    const int it = bid >> 5, jt = bid & 31;      // 32x32 grid of 16x16 tiles
    const int l = threadIdx.x;

    if (bid == 0 && l == 0) out[0] = 0.f;        // visible to K2 at kernel boundary

    __shared__ __align__(16) unsigned char Abf[16 * 512];   // 16 rows x 512 B
    __shared__ __align__(16) unsigned char Bbf[16 * 512];

    const float4* Ag = (const float4*)(feats + (size_t)(it * 16) * F);
    const float4* Bg = (const float4*)(feats + (size_t)(jt * 16) * F);

    #pragma unroll
    for (int m = 0; m < 16; ++m) {               // row m, lane l = float4 #l
        const int swz = ((l >> 1) ^ (m & 7)) * 16 + (l & 1) * 8;
        float4 a = Ag[m * 64 + l];
        ushort4 ha = { f2bf(a.x), f2bf(a.y), f2bf(a.z), f2bf(a.w) };
        *(ushort4*)(Abf + m * 512 + swz) = ha;
        float4 b = Bg[m * 64 + l];
        ushort4 hb = { f2bf(b.x), f2bf(b.y), f2bf(b.z), f2bf(b.w) };
        *(ushort4*)(Bbf + m * 512 + swz) = hb;
    }
    // single wave: compiler orders ds_write -> ds_read via lgkmcnt

    const int row_f = l & 15;
    const int kg    = l >> 4;
    f32x4 acc = {0.f, 0.f, 0.f, 0.f};
    #pragma unroll
    for (int kc = 0; kc < 8; ++kc) {
        int cc = (kc * 4 + kg) ^ (row_f & 7);
        frag_ab a = *(const frag_ab*)(Abf + row_f * 512 + cc * 16);
        frag_ab b = *(const frag_ab*)(Bbf + row_f * 512 + cc * 16);
        acc = __builtin_amdgcn_mfma_f32_16x16x32_bf16(a, b, acc, 0, 0, 0);
    }
    // C layout (verified): col = lane&15, row = (lane>>4)*4 + j
    const int col = l & 15;
    #pragma unroll
    for (int j = 0; j < 4; ++j) {
        int row = kg * 4 + j;
        gram[(size_t)(it * 16 + row) * B + jt * 16 + col] = acc[j];
    }
}

// ---- K2: per-row hinge + pattern histogram + direct atomic accumulate -----
// ids in {0,1}^4 -> 16 patterns. Histogram gives ns, nd, AND the global
// valid count V locally, so each block adds (row_sum/cnt)/V to out[0].
__global__ __launch_bounds__(256) void rows_atomic(
    const int* __restrict__ ids, const float* __restrict__ gram,
    float* __restrict__ out)
{
    const int i    = blockIdx.x;
    const int tid  = threadIdx.x;
    const int lane = tid & 63;
    const int wid  = tid >> 6;

    __shared__ unsigned short pat[B];
    __shared__ float invs[B];
    __shared__ float vals[B];
    __shared__ int   cnt16[16];
    __shared__ unsigned long long cmask[8];
    __shared__ int   coff[9];
    __shared__ float part_s[4];

    if (tid < 16) cnt16[tid] = 0;
    __syncthreads();

    #pragma unroll
    for (int q = 0; q < 2; ++q) {
        int j = tid + q * 256;
        int4 v = ((const int4*)ids)[j];
        int p = (v.x & 1) | ((v.y & 1) << 1) | ((v.z & 1) << 2) | ((v.w & 1) << 3);
        pat[j] = (unsigned short)p;
        atomicAdd(&cnt16[p], 1);                  // LDS atomic, deterministic
        float dg = gram[(size_t)j * 513];         // gram[j][j]
        invs[j] = 1.f / fmaxf(sqrtf(dg + EPSF), EPSF);
    }
    __syncthreads();

    const int   pi   = pat[i];
    const float invi = invs[i];
    const int   ns   = cnt16[pi] - 1;             // same-pattern rows minus self
    const int   nd   = (B - 1) - ns;

    // ballot-compact sim cos values (proven pattern)
    #pragma unroll
    for (int cc = 0; cc < 2; ++cc) {
        int chunk = wid * 2 + cc;
        int j = chunk * 64 + lane;
        unsigned long long m = __ballot(pat[j] == pi && j != i);
        if (lane == 0) cmask[chunk] = m;
    }
    __syncthreads();
    if (tid == 0) {
        int a = 0;
        #pragma unroll
        for (int c = 0; c < 8; ++c) { coff[c] = a; a += (int)__popcll(cmask[c]); }
        coff[8] = a;
    }
    __syncthreads();
    #pragma unroll
    for (int cc = 0; cc < 2; ++cc) {
        int chunk = wid * 2 + cc;
        int j = chunk * 64 + lane;
        unsigned long long m = cmask[chunk];
        if ((m >> lane) & 1ull) {
            int pos = coff[chunk] + (int)__popcll(m & ((1ull << lane) - 1ull));
            vals[pos] = gram[(size_t)i * B + j] * invi * invs[j];
        }
    }
    __syncthreads();

    // negatives: thread owns k = tid, tid+256 (pattern != pi; j==i auto-excluded)
    const int p0 = pat[tid], p1 = pat[tid + 256];
    const bool m0 = (p0 != pi), m1 = (p1 != pi);
    const float c0 = gram[(size_t)i * B + tid]       * invi * invs[tid];
    const float c1 = gram[(size_t)i * B + tid + 256] * invi * invs[tid + 256];
    const float b0 = 0.15f * (float)__popc(p0 ^ pi) + c0;
    const float b1 = 0.15f * (float)__popc(p1 ^ pi) + c1;

    float s = 0.f;
    for (int t = 0; t < ns; ++t) {                // ~31 iters, broadcast LDS read
        float a = vals[t];
        if (m0) s += fmaxf(0.f, b0 - a);
        if (m1) s += fmaxf(0.f, b1 - a);
    }
    #pragma unroll
    for (int o = 32; o > 0; o >>= 1) s += __shfl_down(s, o);
    if (lane == 0) part_s[wid] = s;
    __syncthreads();
    if (tid == 0) {
        float tot = part_s[0] + part_s[1] + part_s[2] + part_s[3];
        int V = 0;                                 // global valid-row count
        #pragma unroll
        for (int p = 0; p < 16; ++p) {
            int c = cnt16[p];
            if (c >= 2 && c < B) V += c;           // ns>0 && nd>0 for those rows
        }
        long cnt = (long)ns * (long)nd;
        if (cnt > 0)
            atomicAdd(out, (tot / (float)cnt) / (float)V);
    }
}

extern "C" void kernel_launch(void* const* d_in, const int* in_sizes, int n_in,
                              void* d_out, int out_size, void* d_ws, size_t ws_size,
                              hipStream_t stream) {
    const int*   ids   = (const int*)d_in[0];
    const float* feats = (const float*)d_in[1];
    float* out = (float*)d_out;

    float* gram = (float*)d_ws;                    // 1 MB

    hipLaunchKernelGGL(gram_mfma, dim3(32 * 32), dim3(64), 0, stream,
                       feats, gram, out);
    hipLaunchKernelGGL(rows_atomic, dim3(B), dim3(256), 0, stream,
                       ids, gram, out);
}

// Round 10
// 15.478 us; speedup vs baseline: 1.3374x; 1.3374x over previous
//
#include <hip/hip_runtime.h>
#include <math.h>

#define EPSF 1e-8f

constexpr int B = 512;
constexpr int F = 256;

using frag_ab = __attribute__((ext_vector_type(8))) short;   // 8 bf16
using f32x4   = __attribute__((ext_vector_type(4))) float;

__device__ __forceinline__ unsigned short f2bf(float f) {
    unsigned int u = __float_as_uint(f);
    unsigned int r = (u + 0x7fffu + ((u >> 16) & 1u)) >> 16;   // RNE
    return (unsigned short)r;
}

// ---- K1: bf16 Gram tile GEMM, 1 wave per 16x16 tile, 1024 blocks ----------
// R9's proven kernel; diagonal tiles additionally emit invs[row] from the
// Gram diagonal (1 lane per row) — replaces the whole norm kernel.
__global__ __launch_bounds__(64) void gram_mfma(
    const float* __restrict__ feats, float* __restrict__ gram,
    float* __restrict__ invs)
{
    const int bid = blockIdx.x;
    const int it = bid >> 5, jt = bid & 31;      // 32x32 grid of 16x16 tiles
    const int l = threadIdx.x;

    __shared__ __align__(16) unsigned char Abf[16 * 512];   // 16 rows x 512 B
    __shared__ __align__(16) unsigned char Bbf[16 * 512];

    const float4* Ag = (const float4*)(feats + (size_t)(it * 16) * F);
    const float4* Bg = (const float4*)(feats + (size_t)(jt * 16) * F);

    #pragma unroll
    for (int m = 0; m < 16; ++m) {               // row m, lane l = float4 #l
        const int swz = ((l >> 1) ^ (m & 7)) * 16 + (l & 1) * 8;
        float4 a = Ag[m * 64 + l];
        ushort4 ha = { f2bf(a.x), f2bf(a.y), f2bf(a.z), f2bf(a.w) };
        *(ushort4*)(Abf + m * 512 + swz) = ha;
        float4 b = Bg[m * 64 + l];
        ushort4 hb = { f2bf(b.x), f2bf(b.y), f2bf(b.z), f2bf(b.w) };
        *(ushort4*)(Bbf + m * 512 + swz) = hb;
    }
    // single wave: compiler orders ds_write -> ds_read via lgkmcnt

    const int row_f = l & 15;
    const int kg    = l >> 4;
    f32x4 acc = {0.f, 0.f, 0.f, 0.f};
    #pragma unroll
    for (int kc = 0; kc < 8; ++kc) {
        int cc = (kc * 4 + kg) ^ (row_f & 7);
        frag_ab a = *(const frag_ab*)(Abf + row_f * 512 + cc * 16);
        frag_ab b = *(const frag_ab*)(Bbf + row_f * 512 + cc * 16);
        acc = __builtin_amdgcn_mfma_f32_16x16x32_bf16(a, b, acc, 0, 0, 0);
    }
    // C layout (verified): col = lane&15, row = (lane>>4)*4 + j
    const int col = l & 15;
    #pragma unroll
    for (int j = 0; j < 4; ++j) {
        int row = kg * 4 + j;
        float v = acc[j];
        gram[(size_t)(it * 16 + row) * B + jt * 16 + col] = v;
        if (it == jt && col == row)              // gram[r][r] -> inverse norm
            invs[it * 16 + row] = 1.f / fmaxf(sqrtf(v + EPSF), EPSF);
    }
}

// ---- K2: per-row hinge sums (R7 rows + pattern margins + coalesced invs) --
__global__ __launch_bounds__(256) void rows_kernel(
    const int* __restrict__ ids, const float* __restrict__ gram,
    const float* __restrict__ invs,
    float* __restrict__ rowloss, int* __restrict__ rowvalid)
{
    const int i    = blockIdx.x;
    const int tid  = threadIdx.x;
    const int lane = tid & 63;
    const int wid  = tid >> 6;

    __shared__ unsigned char pat[B];
    __shared__ float sinv[B];
    __shared__ float vals[B];
    __shared__ unsigned long long cmask[8];
    __shared__ int   coff[9];
    __shared__ float part_s[4];

    #pragma unroll
    for (int q = 0; q < 2; ++q) {
        int j = tid + q * 256;
        int4 v = ((const int4*)ids)[j];
        pat[j] = (unsigned char)((v.x & 1) | ((v.y & 1) << 1)
                               | ((v.z & 1) << 2) | ((v.w & 1) << 3));
        sinv[j] = invs[j];                        // coalesced
    }
    __syncthreads();

    const int   pi   = pat[i];
    const float invi = sinv[i];

    // ballot-compact sim cos values (proven pattern)
    #pragma unroll
    for (int cc = 0; cc < 2; ++cc) {
        int chunk = wid * 2 + cc;
        int j = chunk * 64 + lane;
        unsigned long long m = __ballot(pat[j] == pi && j != i);
        if (lane == 0) cmask[chunk] = m;
    }
    __syncthreads();
    if (tid == 0) {
        int a = 0;
        #pragma unroll
        for (int c = 0; c < 8; ++c) { coff[c] = a; a += (int)__popcll(cmask[c]); }
        coff[8] = a;
    }
    __syncthreads();
    #pragma unroll
    for (int cc = 0; cc < 2; ++cc) {
        int chunk = wid * 2 + cc;
        int j = chunk * 64 + lane;
        unsigned long long m = cmask[chunk];
        if ((m >> lane) & 1ull) {
            int pos = coff[chunk] + (int)__popcll(m & ((1ull << lane) - 1ull));
            vals[pos] = gram[(size_t)i * B + j] * invi * sinv[j];
        }
    }
    __syncthreads();

    const int ns = coff[8];
    const int p0 = pat[tid], p1 = pat[tid + 256];
    const bool m0 = (p0 != pi), m1 = (p1 != pi);  // j==i auto-excluded (p==pi)
    const float c0 = gram[(size_t)i * B + tid]       * invi * sinv[tid];
    const float c1 = gram[(size_t)i * B + tid + 256] * invi * sinv[tid + 256];
    const float b0 = 0.15f * (float)__popc(p0 ^ pi) + c0;
    const float b1 = 0.15f * (float)__popc(p1 ^ pi) + c1;

    float s = 0.f;
    for (int t = 0; t < ns; ++t) {                // ~31 iters, broadcast LDS read
        float a = vals[t];
        if (m0) s += fmaxf(0.f, b0 - a);
        if (m1) s += fmaxf(0.f, b1 - a);
    }
    #pragma unroll
    for (int o = 32; o > 0; o >>= 1) s += __shfl_down(s, o);
    if (lane == 0) part_s[wid] = s;
    __syncthreads();
    if (tid == 0) {
        float tot = part_s[0] + part_s[1] + part_s[2] + part_s[3];
        const int nd = (B - 1) - ns;              // j != i is sim xor dif
        long cnt = (long)ns * (long)nd;
        rowloss[i]  = (cnt > 0) ? tot / (float)cnt : 0.f;
        rowvalid[i] = (cnt > 0) ? 1 : 0;
    }
}

// ---- K3: final mean over valid rows (verbatim) ----------------------------
__global__ __launch_bounds__(256) void finalize_kernel(
    const float* __restrict__ rowloss, const int* __restrict__ rowvalid,
    float* __restrict__ out)
{
    const int tid  = threadIdx.x;
    const int lane = tid & 63;
    const int wid  = tid >> 6;
    __shared__ float sb[4], vb[4];

    float s = rowloss[tid] + rowloss[tid + 256];
    float v = (float)(rowvalid[tid] + rowvalid[tid + 256]);
    #pragma unroll
    for (int o = 32; o > 0; o >>= 1) {
        s += __shfl_down(s, o);
        v += __shfl_down(v, o);
    }
    if (lane == 0) { sb[wid] = s; vb[wid] = v; }
    __syncthreads();
    if (tid == 0) {
        float ts = sb[0] + sb[1] + sb[2] + sb[3];
        float tv = vb[0] + vb[1] + vb[2] + vb[3];
        out[0] = ts / fmaxf(tv, 1.f);
    }
}

extern "C" void kernel_launch(void* const* d_in, const int* in_sizes, int n_in,
                              void* d_out, int out_size, void* d_ws, size_t ws_size,
                              hipStream_t stream) {
    const int*   ids   = (const int*)d_in[0];
    const float* feats = (const float*)d_in[1];
    float* out = (float*)d_out;

    char* ws = (char*)d_ws;
    float* gram     = (float*)ws;                           // 1 MB
    float* invs     = (float*)(ws + (1u << 20));            // 2 KB
    float* rowloss  = (float*)(ws + (1u << 20) + 2048);     // 2 KB
    int*   rowvalid = (int*)(ws + (1u << 20) + 4096);       // 2 KB

    hipLaunchKernelGGL(gram_mfma, dim3(32 * 32), dim3(64), 0, stream,
                       feats, gram, invs);
    hipLaunchKernelGGL(rows_kernel, dim3(B), dim3(256), 0, stream,
                       ids, gram, invs, rowloss, rowvalid);
    hipLaunchKernelGGL(finalize_kernel, dim3(1), dim3(256), 0, stream,
                       rowloss, rowvalid, out);
}